// Round 8
// baseline (411.039 us; speedup 1.0000x reference)
//
#include <hip/hip_runtime.h>
#include <math.h>

typedef __attribute__((ext_vector_type(8))) short bf16x8;
typedef __attribute__((ext_vector_type(4))) float f32x4;

#define NROWS 4096
#define SHORTLIST 2000
#define HEADC 2002
#define CUT1 10000
#define C0_CLS 8000
#define C1_CLS 40000
#define L2E 1.4426950408889634f
#define LN2 0.6931471805599453f

// partial-split counts (= gridDim.x of the three gemm_lse launches)
#define NH_P  16
#define NC0_P 63
#define NC1_P 313

__device__ __forceinline__ float fexp2(float x) {
#if __has_builtin(__builtin_amdgcn_exp2f)
  return __builtin_amdgcn_exp2f(x);
#else
  return exp2f(x);
#endif
}

__device__ __forceinline__ unsigned short f2b(float f) {
  unsigned u = __float_as_uint(f);
  unsigned r = (u + 0x7FFFu + ((u >> 16) & 1u)) >> 16;
  return (unsigned short)r;
}
__device__ __forceinline__ float b2f(unsigned short u) {
  return __uint_as_float(((unsigned)u) << 16);
}

// async global->LDS, 16B per lane (dest must be wave-uniform base + lane*16)
__device__ __forceinline__ void gload_lds16(const void* g, void* l) {
  __builtin_amdgcn_global_load_lds(
      (const __attribute__((address_space(1))) void*)g,
      (__attribute__((address_space(3))) void*)l,
      16, 0, 0);
}

// bijective XCD-aware block swizzle (requires gridDim.x*gridDim.y % 8 == 0)
__device__ __forceinline__ void xcd_swz(int& bx, int& by) {
  const int gx = gridDim.x;
  const int nwg = gx * gridDim.y;
  const int orig = by * gx + bx;
  const int wg = (orig & 7) * (nwg >> 3) + (orig >> 3);
  bx = wg % gx;
  by = wg / gx;
}

// ---------------------------------------------------------------------------
// All f32->bf16 conversions in ONE launch.
// ---------------------------------------------------------------------------
__global__ __launch_bounds__(256) void cvt_all(
    const float* __restrict__ s0, unsigned short* __restrict__ d0,  // x
    const float* __restrict__ s1, unsigned short* __restrict__ d1,  // W1
    const float* __restrict__ s2, unsigned short* __restrict__ d2,  // W2
    const float* __restrict__ s3, unsigned short* __restrict__ d3,  // W3
    const float* __restrict__ s4, unsigned short* __restrict__ d4,  // head_W
    const float* __restrict__ s5, unsigned short* __restrict__ d5,  // t0a
    const float* __restrict__ s6, unsigned short* __restrict__ d6,  // t0b
    const float* __restrict__ s7, unsigned short* __restrict__ d7,  // t1a
    const float* __restrict__ s8, unsigned short* __restrict__ d8)  // t1b
{
  const float* src; unsigned short* dst; int n4;
  switch (blockIdx.y) {
    case 0: src = s0; dst = d0; n4 = 4096 * 512 / 4;   break;
    case 1: src = s1; dst = d1; n4 = 2048 * 512 / 4;   break;
    case 2: src = s2; dst = d2; n4 = 128 * 2048 / 4;   break;
    case 3: src = s3; dst = d3; n4 = 512 * 128 / 4;    break;
    case 4: src = s4; dst = d4; n4 = HEADC * 512 / 4;  break;
    case 5: src = s5; dst = d5; n4 = 128 * 512 / 4;    break;
    case 6: src = s6; dst = d6; n4 = 8000 * 128 / 4;   break;
    case 7: src = s7; dst = d7; n4 = 32 * 512 / 4;     break;
    default: src = s8; dst = d8; n4 = 40000 * 32 / 4;  break;
  }
  for (int i = blockIdx.x * 256 + threadIdx.x; i < n4; i += 256 * gridDim.x) {
    float4 v = ((const float4*)src)[i];
    ushort4 o;
    o.x = f2b(v.x); o.y = f2b(v.y); o.z = f2b(v.z); o.w = f2b(v.w);
    ((ushort4*)dst)[i] = o;
  }
}

// ---------------------------------------------------------------------------
// LDS-staged MFMA GEMM (m97 anatomy, global_load_lds width=16):
// 128x128 tile, BK=32, 4 waves (2x2). SplitK via blockIdx.z.
// SCL multiplies the (post-act) output by log2(e).
// ---------------------------------------------------------------------------
template<bool BIAS, bool RELU, bool F32OUT, bool SCL>
__global__ __launch_bounds__(256) void gemm_lds(
    const unsigned short* __restrict__ A, const unsigned short* __restrict__ W,
    const float* __restrict__ bias, void* __restrict__ outp,
    int M, int N, int lda, int Kseg)
{
  __shared__ __align__(16) unsigned short As[128 * 32];
  __shared__ __align__(16) unsigned short Bs[128 * 32];

  int bx = blockIdx.x, by = blockIdx.y;
  xcd_swz(bx, by);

  const int tid  = threadIdx.x;
  const int lane = tid & 63;
  const int wv   = tid >> 6;
  const int cl   = lane & 15;
  const int ko   = lane >> 4;
  const int wr   = (wv >> 1) * 64;
  const int wc   = (wv & 1) * 64;
  const int row0 = by * 128;
  const int col0 = bx * 128;
  const int koff = blockIdx.z * Kseg;

  const int sr0 = tid >> 2;   // staging row 0..63 (LDS byte off = tid*16)
  const int ssl = tid & 3;    // 16B slot

  f32x4 acc[4][4];
#pragma unroll
  for (int p = 0; p < 4; ++p)
#pragma unroll
    for (int q = 0; q < 4; ++q) acc[p][q] = (f32x4){0.f, 0.f, 0.f, 0.f};

  const unsigned short* aSrc = A + (size_t)(row0 + sr0) * lda + koff + ssl * 8;
  const unsigned short* bSrc = W + (size_t)(col0 + sr0) * lda + koff + ssl * 8;
  const size_t half = (size_t)64 * lda;

  const int nK = Kseg / 32;
  for (int ks = 0; ks < nK; ++ks) {
    const int kb = ks * 32;
    gload_lds16(aSrc + kb,        &As[tid * 8]);
    gload_lds16(aSrc + kb + half, &As[2048 + tid * 8]);
    gload_lds16(bSrc + kb,        &Bs[tid * 8]);
    gload_lds16(bSrc + kb + half, &Bs[2048 + tid * 8]);
    __syncthreads();   // drains vmcnt -> LDS complete

    bf16x8 aF[4], bF[4];
#pragma unroll
    for (int p = 0; p < 4; ++p)
      aF[p] = *(const bf16x8*)&As[(size_t)(wr + p * 16 + cl) * 32 + ko * 8];
#pragma unroll
    for (int q = 0; q < 4; ++q)
      bF[q] = *(const bf16x8*)&Bs[(size_t)(wc + q * 16 + cl) * 32 + ko * 8];
#pragma unroll
    for (int p = 0; p < 4; ++p)
#pragma unroll
      for (int q = 0; q < 4; ++q)
        acc[p][q] = __builtin_amdgcn_mfma_f32_16x16x32_bf16(aF[p], bF[q], acc[p][q], 0, 0, 0);
    __syncthreads();   // all reads done before next tile's async writes
  }

  if constexpr (F32OUT) {
    float* P = (float*)outp + (size_t)blockIdx.z * M * N;
#pragma unroll
    for (int q = 0; q < 4; ++q) {
      const int col = col0 + wc + q * 16 + cl;
#pragma unroll
      for (int p = 0; p < 4; ++p)
#pragma unroll
        for (int j = 0; j < 4; ++j) {
          const int R = row0 + wr + p * 16 + 4 * ko + j;
          P[(size_t)R * N + col] = acc[p][q][j];
        }
    }
  } else {
    unsigned short* C = (unsigned short*)outp;
#pragma unroll
    for (int q = 0; q < 4; ++q) {
      const int col = col0 + wc + q * 16 + cl;
      float bs = 0.f;
      if (BIAS) bs = bias[col];
#pragma unroll
      for (int p = 0; p < 4; ++p)
#pragma unroll
        for (int j = 0; j < 4; ++j) {
          const int R = row0 + wr + p * 16 + 4 * ko + j;
          float v = acc[p][q][j] + bs;
          if (RELU) v = fmaxf(v, 0.f);
          if (SCL)  v *= L2E;
          C[(size_t)R * N + col] = f2b(v);
        }
    }
  }
}

// ---------------------------------------------------------------------------
// Split-K reduce: out_bf16 = act(sum_z P[z] + bias). Vectorized x4.
// ---------------------------------------------------------------------------
template<int SK, bool BIAS, bool RELU>
__global__ __launch_bounds__(256) void splitk_reduce(
    const float* __restrict__ P, const float* __restrict__ bias,
    unsigned short* __restrict__ out, int MN4, int N)
{
  const int i = blockIdx.x * 256 + threadIdx.x;
  if (i >= MN4) return;
  float4 v = ((const float4*)P)[i];
#pragma unroll
  for (int z = 1; z < SK; ++z) {
    float4 p = ((const float4*)(P + (size_t)z * MN4 * 4))[i];
    v.x += p.x; v.y += p.y; v.z += p.z; v.w += p.w;
  }
  if (BIAS) {
    const int col = (i % (N / 4)) * 4;
    float4 b = *(const float4*)(bias + col);
    v.x += b.x; v.y += b.y; v.z += b.z; v.w += b.w;
  }
  if (RELU) {
    v.x = fmaxf(v.x, 0.f); v.y = fmaxf(v.y, 0.f);
    v.z = fmaxf(v.z, 0.f); v.w = fmaxf(v.w, 0.f);
  }
  ushort4 o;
  o.x = f2b(v.x); o.y = f2b(v.y); o.z = f2b(v.z); o.w = f2b(v.w);
  ((ushort4*)out)[i] = o;
}

// ---------------------------------------------------------------------------
// Unified class-dim GEMM + fused per-row LSE epilogue (log2 domain).
// A is log2(e)-pre-scaled; W clamped-staged; cols >= C masked to -inf.
// Partials pm/ps laid out [gridDim.x][NROWS]. lda = K (runtime, %32==0).
// ---------------------------------------------------------------------------
template<bool BIAS>
__global__ __launch_bounds__(256) void gemm_lse(
    const unsigned short* __restrict__ A,   // [4096][lda], log2-scaled
    const unsigned short* __restrict__ W,   // [C][lda]
    const float* __restrict__ bias,         // BIAS only
    int C, int lda,
    float* __restrict__ pm, float* __restrict__ ps)
{
  __shared__ __align__(16) unsigned short As[128 * 32];
  __shared__ __align__(16) unsigned short Bs[128 * 32];
  __shared__ float lm[4][64], ls[4][64];

  int bx = blockIdx.x, by = blockIdx.y;
  xcd_swz(bx, by);

  const int tid  = threadIdx.x;
  const int lane = tid & 63;
  const int wv   = tid >> 6;
  const int cl   = lane & 15;
  const int ko   = lane >> 4;
  const int wr   = (wv >> 1) * 64;
  const int wc   = (wv & 1) * 64;
  const int row0 = by * 128;
  const int col0 = bx * 128;

  const int sr0 = tid >> 2;
  const int ssl = tid & 3;

  f32x4 acc[4][4];
#pragma unroll
  for (int p = 0; p < 4; ++p)
#pragma unroll
    for (int q = 0; q < 4; ++q) acc[p][q] = (f32x4){0.f, 0.f, 0.f, 0.f};

  const unsigned short* aSrc  = A + (size_t)(row0 + sr0) * lda + ssl * 8;
  const unsigned short* bSrc0 = W + (size_t)min(col0 + sr0,      C - 1) * lda + ssl * 8;
  const unsigned short* bSrc1 = W + (size_t)min(col0 + sr0 + 64, C - 1) * lda + ssl * 8;
  const size_t half = (size_t)64 * lda;

  const int nK = lda / 32;
  for (int ks = 0; ks < nK; ++ks) {
    const int kb = ks * 32;
    gload_lds16(aSrc + kb,        &As[tid * 8]);
    gload_lds16(aSrc + kb + half, &As[2048 + tid * 8]);
    gload_lds16(bSrc0 + kb,       &Bs[tid * 8]);
    gload_lds16(bSrc1 + kb,       &Bs[2048 + tid * 8]);
    __syncthreads();

    bf16x8 aF[4], bF[4];
#pragma unroll
    for (int p = 0; p < 4; ++p)
      aF[p] = *(const bf16x8*)&As[(size_t)(wr + p * 16 + cl) * 32 + ko * 8];
#pragma unroll
    for (int q = 0; q < 4; ++q)
      bF[q] = *(const bf16x8*)&Bs[(size_t)(wc + q * 16 + cl) * 32 + ko * 8];
#pragma unroll
    for (int p = 0; p < 4; ++p)
#pragma unroll
      for (int q = 0; q < 4; ++q)
        acc[p][q] = __builtin_amdgcn_mfma_f32_16x16x32_bf16(aF[p], bF[q], acc[p][q], 0, 0, 0);
    __syncthreads();
  }

  // ---- fused LSE epilogue (log2 domain) ----
  float bl2[4]; int colq[4];
#pragma unroll
  for (int q = 0; q < 4; ++q) {
    colq[q] = col0 + wc + q * 16 + cl;
    bl2[q] = BIAS ? bias[min(colq[q], C - 1)] * L2E : 0.f;
  }

  float mr[4][4], sr_[4][4];
#pragma unroll
  for (int p = 0; p < 4; ++p)
#pragma unroll
    for (int j = 0; j < 4; ++j) {
      float vv[4];
#pragma unroll
      for (int q = 0; q < 4; ++q) {
        float v = BIAS ? (acc[p][q][j] + bl2[q]) : acc[p][q][j];
        if (colq[q] >= C) v = -1e30f;
        vv[q] = v;
      }
      const float mm = fmaxf(fmaxf(vv[0], vv[1]), fmaxf(vv[2], vv[3]));
      float ss = 0.f;
#pragma unroll
      for (int q = 0; q < 4; ++q) ss += fexp2(vv[q] - mm);
      mr[p][j] = mm;
      sr_[p][j] = ss;
    }

#pragma unroll
  for (int mask = 1; mask <= 8; mask <<= 1) {
#pragma unroll
    for (int p = 0; p < 4; ++p)
#pragma unroll
      for (int j = 0; j < 4; ++j) {
        const float mo = __shfl_xor(mr[p][j], mask);
        const float so = __shfl_xor(sr_[p][j], mask);
        const float mn = fmaxf(mr[p][j], mo);
        sr_[p][j] = sr_[p][j] * fexp2(mr[p][j] - mn) + so * fexp2(mo - mn);
        mr[p][j] = mn;
      }
  }

  if (cl == 0) {
#pragma unroll
    for (int p = 0; p < 4; ++p)
#pragma unroll
      for (int j = 0; j < 4; ++j) {
        lm[wv][p * 16 + 4 * ko + j] = mr[p][j];
        ls[wv][p * 16 + 4 * ko + j] = sr_[p][j];
      }
  }
  __syncthreads();
  if (tid < 128) {
    const int pair = tid >> 6, idx = tid & 63;
    const float m0 = lm[pair * 2][idx], m1 = lm[pair * 2 + 1][idx];
    const float M = fmaxf(m0, m1);
    const float S = ls[pair * 2][idx] * fexp2(m0 - M) + ls[pair * 2 + 1][idx] * fexp2(m1 - M);
    const int grow = row0 + tid;
    pm[(size_t)bx * NROWS + grow] = M;
    ps[(size_t)bx * NROWS + grow] = S;
  }
}

// ---------------------------------------------------------------------------
// LDS-free MFMA GEMM (kept for the tiny N=32 projection).
// ---------------------------------------------------------------------------
template<int WR, int WC, bool BIAS, bool RELU>
__global__ __launch_bounds__(256) void gemm_mfma(
    const unsigned short* __restrict__ A, const unsigned short* __restrict__ W,
    const float* __restrict__ bias, unsigned short* __restrict__ C,
    int M, int N, int K)
{
  const int lane = threadIdx.x & 63;
  const int wv   = threadIdx.x >> 6;
  const int cl   = lane & 15;
  const int ko   = lane >> 4;
  const int rw   = (blockIdx.y * WR + (wv / WC)) * 64;
  const int cw   = (blockIdx.x * WC + (wv % WC)) * 32;

  f32x4 acc[4][2];
#pragma unroll
  for (int p = 0; p < 4; ++p)
#pragma unroll
    for (int q = 0; q < 2; ++q) acc[p][q] = (f32x4){0.f, 0.f, 0.f, 0.f};

  const unsigned short* ap = A + (size_t)(rw + cl) * K + ko * 8;
  const unsigned short* bp = W + (size_t)(cw + cl) * K + ko * 8;
  const size_t rstep = (size_t)16 * K;

#pragma unroll 2
  for (int kb = 0; kb < K; kb += 32) {
    bf16x8 a[4], b[2];
#pragma unroll
    for (int p = 0; p < 4; ++p) a[p] = *(const bf16x8*)(ap + p * rstep + kb);
#pragma unroll
    for (int q = 0; q < 2; ++q) b[q] = *(const bf16x8*)(bp + q * rstep + kb);
#pragma unroll
    for (int p = 0; p < 4; ++p)
#pragma unroll
      for (int q = 0; q < 2; ++q)
        acc[p][q] = __builtin_amdgcn_mfma_f32_16x16x32_bf16(a[p], b[q], acc[p][q], 0, 0, 0);
  }

#pragma unroll
  for (int q = 0; q < 2; ++q) {
    const int col = cw + q * 16 + cl;
    if (col >= N) continue;
    float bs = 0.f;
    if (BIAS) bs = bias[col];
#pragma unroll
    for (int p = 0; p < 4; ++p) {
#pragma unroll
      for (int j = 0; j < 4; ++j) {
        const int R = rw + p * 16 + 4 * ko + j;
        float v = acc[p][q][j] + bs;
        if (RELU) v = fmaxf(v, 0.f);
        C[(size_t)R * N + col] = f2b(v);
      }
    }
  }
}

// ---------------------------------------------------------------------------
// Target / cluster-logit gather (log2 domain: inputs pre-scaled, bias * L2E).
// ---------------------------------------------------------------------------
__global__ __launch_bounds__(256) void gather_kernel(
    const unsigned short* __restrict__ Sb,
    const unsigned short* __restrict__ hWb,
    const float* __restrict__ head_b,
    const unsigned short* __restrict__ h0b,
    const unsigned short* __restrict__ t0bb,
    const unsigned short* __restrict__ h1b,
    const unsigned short* __restrict__ t1bb,
    const int* __restrict__ t,
    float* __restrict__ gsh, float* __restrict__ gc0, float* __restrict__ gc1,
    float* __restrict__ tg0, float* __restrict__ tg1)
{
  const int lane = threadIdx.x & 63;
  const int row  = blockIdx.x * 4 + (threadIdx.x >> 6);
  const int tv   = t[row];
  const int ch   = min(max(tv, 0), SHORTLIST - 1);
  const int c0   = min(max(tv - SHORTLIST, 0), C0_CLS - 1);
  const int c1   = min(max(tv - CUT1, 0), C1_CLS - 1);

  float acc[5] = {0.f, 0.f, 0.f, 0.f, 0.f};

  {
    bf16x8 sv = *(const bf16x8*)(Sb + (size_t)row * 512 + lane * 8);
    bf16x8 w0 = *(const bf16x8*)(hWb + (size_t)ch * 512 + lane * 8);
    bf16x8 w1 = *(const bf16x8*)(hWb + (size_t)SHORTLIST * 512 + lane * 8);
    bf16x8 w2 = *(const bf16x8*)(hWb + (size_t)(SHORTLIST + 1) * 512 + lane * 8);
#pragma unroll
    for (int e = 0; e < 8; ++e) {
      const float sf = b2f((unsigned short)sv[e]);
      acc[0] = fmaf(sf, b2f((unsigned short)w0[e]), acc[0]);
      acc[1] = fmaf(sf, b2f((unsigned short)w1[e]), acc[1]);
      acc[2] = fmaf(sf, b2f((unsigned short)w2[e]), acc[2]);
    }
  }
  if (lane < 16) {
    bf16x8 hv = *(const bf16x8*)(h0b + (size_t)row * 128 + lane * 8);
    bf16x8 wv = *(const bf16x8*)(t0bb + (size_t)c0 * 128 + lane * 8);
#pragma unroll
    for (int e = 0; e < 8; ++e)
      acc[3] = fmaf(b2f((unsigned short)hv[e]), b2f((unsigned short)wv[e]), acc[3]);
  }
  if (lane < 4) {
    bf16x8 hv = *(const bf16x8*)(h1b + (size_t)row * 32 + lane * 8);
    bf16x8 wv = *(const bf16x8*)(t1bb + (size_t)c1 * 32 + lane * 8);
#pragma unroll
    for (int e = 0; e < 8; ++e)
      acc[4] = fmaf(b2f((unsigned short)hv[e]), b2f((unsigned short)wv[e]), acc[4]);
  }

#pragma unroll
  for (int mask = 1; mask < 64; mask <<= 1)
#pragma unroll
    for (int k = 0; k < 5; ++k) acc[k] += __shfl_xor(acc[k], mask);

  if (lane == 0) {
    gsh[row] = acc[0] + head_b[ch] * L2E;
    gc0[row] = acc[1] + head_b[SHORTLIST] * L2E;
    gc1[row] = acc[2] + head_b[SHORTLIST + 1] * L2E;
    tg0[row] = acc[3];
    tg1[row] = acc[4];
  }
}

// ---------------------------------------------------------------------------
// Combine partials (all log2 domain); single *LN2 at the end.
// ---------------------------------------------------------------------------
__global__ __launch_bounds__(256) void combine_kernel(
    const int* __restrict__ t,
    const float* __restrict__ pmh, const float* __restrict__ psh,
    const float* __restrict__ gsh, const float* __restrict__ gc0,
    const float* __restrict__ gc1,
    const float* __restrict__ pm0, const float* __restrict__ ps0,
    const float* __restrict__ tg0,
    const float* __restrict__ pm1, const float* __restrict__ ps1,
    const float* __restrict__ tg1,
    float* __restrict__ out)
{
  const int r = blockIdx.x * 256 + threadIdx.x;
  if (r >= NROWS) return;

  float M = -1e30f, S = 0.f;
  for (int c = 0; c < NH_P; ++c) M = fmaxf(M, pmh[c * NROWS + r]);
  for (int c = 0; c < NH_P; ++c) S += psh[c * NROWS + r] * fexp2(pmh[c * NROWS + r] - M);
  const float hl2 = M + log2f(S);

  const int tv = t[r];
  float o2;
  if (tv < SHORTLIST) {
    o2 = gsh[r] - hl2;
  } else if (tv < CUT1) {
    float M0 = -1e30f, S0 = 0.f;
    for (int c = 0; c < NC0_P; ++c) M0 = fmaxf(M0, pm0[c * NROWS + r]);
    for (int c = 0; c < NC0_P; ++c) S0 += ps0[c * NROWS + r] * fexp2(pm0[c * NROWS + r] - M0);
    o2 = (gc0[r] - hl2) + (tg0[r] - (M0 + log2f(S0)));
  } else {
    float M1 = -1e30f, S1 = 0.f;
    for (int c = 0; c < NC1_P; ++c) M1 = fmaxf(M1, pm1[c * NROWS + r]);
    for (int c = 0; c < NC1_P; ++c) S1 += ps1[c * NROWS + r] * fexp2(pm1[c * NROWS + r] - M1);
    o2 = (gc1[r] - hl2) + (tg1[r] - (M1 + log2f(S1)));
  }
  out[r] = o2 * LN2;
}

__global__ __launch_bounds__(256) void loss_kernel(
    const float* __restrict__ out, float* __restrict__ loss)
{
  __shared__ float sred[256];
  const int tid = threadIdx.x;
  float s = 0.f;
  for (int i = tid; i < NROWS; i += 256) s += out[i];
  sred[tid] = s;
  __syncthreads();
  for (int st = 128; st > 0; st >>= 1) {
    if (tid < st) sred[tid] += sred[tid + st];
    __syncthreads();
  }
  if (tid == 0) *loss = -sred[0] / (float)NROWS;
}

// ---------------------------------------------------------------------------
extern "C" void kernel_launch(void* const* d_in, const int* in_sizes, int n_in,
                              void* d_out, int out_size, void* d_ws, size_t ws_size,
                              hipStream_t stream)
{
  const float* x      = (const float*)d_in[0];
  const int*   t      = (const int*)  d_in[1];
  const float* W1     = (const float*)d_in[2];
  const float* b1     = (const float*)d_in[3];
  const float* W2     = (const float*)d_in[4];
  const float* b2     = (const float*)d_in[5];
  const float* W3     = (const float*)d_in[6];
  const float* b3     = (const float*)d_in[7];
  const float* head_W = (const float*)d_in[8];
  const float* head_b = (const float*)d_in[9];
  const float* t0a    = (const float*)d_in[10];
  const float* t0b    = (const float*)d_in[11];
  const float* t1a    = (const float*)d_in[12];
  const float* t1b    = (const float*)d_in[13];

  // ---- workspace layout (bf16 region, then f32 region) ----
  unsigned short* p16 = (unsigned short*)d_ws;
  unsigned short* xb  = p16; p16 += 4096ull * 512;
  unsigned short* W1b = p16; p16 += 2048ull * 512;
  unsigned short* W2b = p16; p16 += 128ull  * 2048;
  unsigned short* W3b = p16; p16 += 512ull  * 128;
  unsigned short* hWb = p16; p16 += (size_t)HEADC * 512;
  unsigned short* t0ab= p16; p16 += 128ull  * 512;
  unsigned short* t0bb= p16; p16 += 8000ull * 128;
  unsigned short* t1ab= p16; p16 += 32ull   * 512;
  unsigned short* t1bb= p16; p16 += 40000ull* 32;
  unsigned short* H1b = p16; p16 += 4096ull * 2048;
  unsigned short* H2b = p16; p16 += 4096ull * 128;
  unsigned short* Sb  = p16; p16 += 4096ull * 512;   // log2-scaled S
  unsigned short* h0b = p16; p16 += 4096ull * 128;   // log2-scaled h0
  unsigned short* h1b = p16; p16 += 4096ull * 32;    // log2-scaled h1

  float* pf  = (float*)p16;
  float* pmh = pf; pf += 4096 * NH_P;
  float* psh = pf; pf += 4096 * NH_P;
  float* pm0 = pf; pf += 4096 * NC0_P;
  float* ps0 = pf; pf += 4096 * NC0_P;
  float* pm1 = pf; pf += 4096 * NC1_P;
  float* ps1 = pf; pf += 4096 * NC1_P;
  float* gsh = pf; pf += 4096;
  float* gc0 = pf; pf += 4096;
  float* gc1 = pf; pf += 4096;
  float* tg0 = pf; pf += 4096;
  float* tg1 = pf; pf += 4096;
  float* Pbuf = pf; pf += 4ull * 4096 * 128;   // split-K partials (reused)

  float* out = (float*)d_out;   // [4096] log-probs, then [1] loss

  const dim3 blk(256);

  // ---- all conversions in one launch ----
  cvt_all<<<dim3(256, 9), blk, 0, stream>>>(
      x, xb, W1, W1b, W2, W2b, W3, W3b, head_W, hWb,
      t0a, t0ab, t0b, t0bb, t1a, t1ab, t1b, t1bb);

  // ---- MLP (LDS-staged MFMA); GEMM3 output scaled by log2(e) ----
  gemm_lds<true, true, false, false><<<dim3(16, 32), blk, 0, stream>>>(
      xb, W1b, b1, H1b, 4096, 2048, 512, 512);
  gemm_lds<false, false, true, false><<<dim3(1, 32, 4), blk, 0, stream>>>(
      H1b, W2b, nullptr, Pbuf, 4096, 128, 2048, 512);
  splitk_reduce<4, true, true><<<dim3(512), blk, 0, stream>>>(
      Pbuf, b2, H2b, 4096 * 128 / 4, 128);
  gemm_lds<true, true, false, true><<<dim3(4, 32), blk, 0, stream>>>(
      H2b, W3b, b3, Sb, 4096, 512, 128, 128);

  // ---- tail low-rank projections (inherit log2 scaling from Sb) ----
  gemm_lds<false, false, true, false><<<dim3(1, 32, 4), blk, 0, stream>>>(
      Sb, t0ab, nullptr, Pbuf, 4096, 128, 512, 128);
  splitk_reduce<4, false, false><<<dim3(512), blk, 0, stream>>>(
      Pbuf, nullptr, h0b, 4096 * 128 / 4, 128);
  gemm_mfma<4, 1, false, false><<<dim3(1, 16), blk, 0, stream>>>(
      Sb, t1ab, nullptr, h1b, 4096, 32, 512);

  // ---- head + tails: unified GEMM + fused LSE epilogue ----
  gemm_lse<true ><<<dim3(NH_P,  32), blk, 0, stream>>>(Sb,  hWb,  head_b, HEADC,  512, pmh, psh);
  gemm_lse<false><<<dim3(NC0_P, 32), blk, 0, stream>>>(h0b, t0bb, nullptr, C0_CLS, 128, pm0, ps0);
  gemm_lse<false><<<dim3(NC1_P, 32), blk, 0, stream>>>(h1b, t1bb, nullptr, C1_CLS, 32,  pm1, ps1);

  // ---- gathered logits (5 dots per row) ----
  gather_kernel<<<dim3(NROWS / 4), blk, 0, stream>>>(
      Sb, hWb, head_b, h0b, t0bb, h1b, t1bb, t, gsh, gc0, gc1, tg0, tg1);

  // ---- combine + loss ----
  combine_kernel<<<dim3((NROWS + 255) / 256), blk, 0, stream>>>(
      t, pmh, psh, gsh, gc0, gc1, pm0, ps0, tg0, pm1, ps1, tg1, out);
  loss_kernel<<<dim3(1), blk, 0, stream>>>(out, out + NROWS);
}